// Round 11
// baseline (197.635 us; speedup 1.0000x reference)
//
#include <hip/hip_runtime.h>
#include <hip/hip_bf16.h>

// GAT layer: out = h = x @ W^T  (N=200000 x 128, fp32 in / fp32 out), then
// E=500 edges: out[dst] += 0.1 * leaky_relu(attn, 0.2) * h[src].
//
// K1 evidence matrix (11 rounds):
//   clean configs (R0/R2/R5-R8/R10): all 2.05-2.46 TB/s regardless of
//     load shape, store shape, depth, barriers, occupancy (R10: 16 w/CU,
//     clean 50/100 MB, still 2.45).
//   R9 scattered loads @ 16 w/CU: SERVICE 3.05 TB/s -- proves the memory
//     system serves this kernel >2.45 when line-level MLP is high
//     (scattered float4 = 16-32 lines/instr vs 8 contiguous; 8 KB/wave in
//     flight vs R10's 2 KB/wave block-shared). R9's loss was traffic:
//     D-layout stores fill each 128B line with TWO instrs -> under
//     pressure, half-written lines evict (WRITE 190 MB) + RFO (FETCH 187).
// R11 = R9's load engine + R10's clean store engine:
//   - scattered per-lane fragment loads, 8 KB/wave, 1-deep prefetch
//   - per-wave LDS transpose stores: 4 passes x 4 rows through a private
//     2 KB scratch -> 1KB-contiguous full-line store instructions
//   - LDS = Ws 32768 (XOR-swizzled) + 4 x 2048 scratch = 40960 = 160K/4
//     -> 4 blocks/CU, 16 waves/CU; no in-loop barriers (scratch private)
// K2/K3 unchanged (race-free two-phase edge update).

typedef __attribute__((ext_vector_type(8))) short bf16x8;   // 8 bf16 = 4 VGPRs
typedef __attribute__((ext_vector_type(4))) float f32x4;

__device__ __forceinline__ bf16x8 pack_bf16x8(float4 v0, float4 v1) {
  union { bf16x8 v; __hip_bfloat16 h[8]; } u;
  u.h[0] = __float2bfloat16(v0.x); u.h[1] = __float2bfloat16(v0.y);
  u.h[2] = __float2bfloat16(v0.z); u.h[3] = __float2bfloat16(v0.w);
  u.h[4] = __float2bfloat16(v1.x); u.h[5] = __float2bfloat16(v1.y);
  u.h[6] = __float2bfloat16(v1.z); u.h[7] = __float2bfloat16(v1.w);
  return u.v;
}

__global__ __launch_bounds__(256, 4) void gat_gemm_kernel(
    const float* __restrict__ x,
    const float* __restrict__ W,
    float* __restrict__ out,
    int N) {
  __shared__ __align__(16) char WsB[32768];   // W bf16, XOR-swizzled rows
  __shared__ __align__(16) char XsB[8192];    // 4 x 2048 per-wave f32 scratch

  const int tid = threadIdx.x;

  // ---- Stage W (128x128 fp32) -> WsB bf16, XOR-swizzled. One-time. ----
  #pragma unroll
  for (int it = 0; it < 16; ++it) {
    int seg = it * 256 + tid;          // 0..4095 4-float segments
    int row = seg >> 5;                // 32 segs per 128-col row
    int o8 = seg & 31;                 // 8-byte slot within row
    float4 v = *reinterpret_cast<const float4*>(&W[row * 128 + o8 * 4]);
    union { ushort4 u4; __hip_bfloat16 h[4]; } wpk;
    wpk.h[0] = __float2bfloat16(v.x);
    wpk.h[1] = __float2bfloat16(v.y);
    wpk.h[2] = __float2bfloat16(v.z);
    wpk.h[3] = __float2bfloat16(v.w);
    *reinterpret_cast<ushort4*>(
        WsB + row * 256 + ((o8 * 8) ^ ((row & 7) << 4))) = wpk.u4;
  }
  __syncthreads();   // one-time; no barriers after this point

  const int wave = tid >> 6;
  const int lane = tid & 63;
  const int m = lane & 15;     // W-frag row (= out col blk) / x row in B-frag
  const int q = lane >> 4;     // quad: k-subchunk q*8, D reg row q*4+j

  char* scr = XsB + wave * 2048;       // private 2 KB store scratch

  // Bijective XCD swizzle (gridDim.x % 8 == 0): XCD gets contiguous range.
  const int nwg = (int)gridDim.x;
  const int bid = (int)blockIdx.x;
  const int swz = (bid & 7) * (nwg >> 3) + (bid >> 3);

  const int tiles = N >> 4;              // 16-row tiles: 12500
  const int gw = nwg * 4;                // total waves = tile stride (4096)
  int t = swz * 4 + wave;
  if (t >= tiles) return;                // wave-uniform; no barriers below

  // Scattered fragment prefetch: lane(m,q) holds x[t*16+m][s*32+q*8 .. +7].
  // 8 float4/lane = 8 KB/wave in flight; ~16-32 lines per instruction.
  float4 raw[8];
  {
    const float* xrow = x + (long)(t * 16 + m) * 128;
    #pragma unroll
    for (int s = 0; s < 4; ++s) {
      raw[2 * s]     = *reinterpret_cast<const float4*>(xrow + s * 32 + q * 8);
      raw[2 * s + 1] = *reinterpret_cast<const float4*>(xrow + s * 32 + q * 8 + 4);
    }
  }

  while (true) {
    // Convert current tile's x to bf16 B-fragments (frees raw for refill).
    bf16x8 af[4];
    #pragma unroll
    for (int s = 0; s < 4; ++s) af[s] = pack_bf16x8(raw[2 * s], raw[2 * s + 1]);

    // Issue next tile's loads now -> in flight across MFMA + store.
    const int tn = t + gw;
    if (tn < tiles) {
      const float* xrow = x + (long)(tn * 16 + m) * 128;
      #pragma unroll
      for (int s = 0; s < 4; ++s) {
        raw[2 * s]     = *reinterpret_cast<const float4*>(xrow + s * 32 + q * 8);
        raw[2 * s + 1] = *reinterpret_cast<const float4*>(xrow + s * 32 + q * 8 + 4);
      }
    }

    // D[r][c] = sum_k W[nt*16+r][k] * x[t*16+c][k] (A=W from LDS, B=x).
    f32x4 acc[8];
    #pragma unroll
    for (int nt = 0; nt < 8; ++nt) acc[nt] = (f32x4){0.f, 0.f, 0.f, 0.f};
    #pragma unroll
    for (int s = 0; s < 4; ++s) {
      #pragma unroll
      for (int nt = 0; nt < 8; ++nt) {
        bf16x8 wfrag = *reinterpret_cast<const bf16x8*>(
            WsB + (nt * 16 + m) * 256 + ((s * 64 + q * 16) ^ ((m & 7) << 4)));
        acc[nt] = __builtin_amdgcn_mfma_f32_16x16x32_bf16(wfrag, af[s],
                                                          acc[nt], 0, 0, 0);
      }
    }

    // ---- clean store: per-wave LDS transpose, 4 passes x 4 rows. ----
    // acc (reg j, lane(m,q)) = out[t*16+m][nt*16+q*4+j]. Pass h covers rows
    // m in [4h,4h+4): those 16 lanes dump all 8 acc f32x4s into scratch
    // (XOR (m&3)<<4 spreads banks); then all 64 lanes read back linearly
    // and store two 1KB-contiguous f32x4 instructions (full-line writes ->
    // no partial-line eviction, no RFO).
    #pragma unroll
    for (int h = 0; h < 4; ++h) {
      if ((m >> 2) == h) {
        #pragma unroll
        for (int nt = 0; nt < 8; ++nt)
          *reinterpret_cast<f32x4*>(
              scr + (m & 3) * 512 +
              (((nt * 64 + q * 16)) ^ ((m & 3) << 4))) = acc[nt];
      }
      asm volatile("s_waitcnt lgkmcnt(0)" ::: "memory");
      __builtin_amdgcn_sched_barrier(0);
      float* oh = out + (long)(t * 16 + h * 4) * 128;
      #pragma unroll
      for (int i = 0; i < 2; ++i) {
        int g = i * 64 + lane;          // 0..127 f32x4 slots of this 2KB pass
        int r = g >> 5, c = g & 31;     // row-in-pass, 16B slot
        f32x4 v = *reinterpret_cast<const f32x4*>(
            scr + r * 512 + ((c * 16) ^ (r << 4)));
        *reinterpret_cast<f32x4*>(oh + g * 4) = v;
      }
      // pass reads done before next pass reuses scratch (within-wave only)
      asm volatile("s_waitcnt lgkmcnt(0)" ::: "memory");
      __builtin_amdgcn_sched_barrier(0);
    }

    if (tn >= tiles) break;
    t = tn;
  }
}

__device__ __forceinline__ int detect_i64(const int* eidx) {
  int or_odd = 0;
  #pragma unroll
  for (int k = 0; k < 16; ++k) or_odd |= eidx[2 * k + 1];
  return or_odd == 0;   // int64 little-endian: high words all zero
}

// Phase A: one block per edge. Read h rows from `out` (pure read), compute
// attn, write contribution vector 0.1*attn*h_src to ws. No races.
__global__ __launch_bounds__(128) void gat_edge_attn(
    const int* __restrict__ eidx,
    const float* __restrict__ a,       // [4, 64]
    const float* __restrict__ h,       // == out, post-GEMM
    float* __restrict__ contrib,       // [E, 128] in ws
    int E) {
  const int e = blockIdx.x;
  const int c = threadIdx.x;
  const bool is64 = detect_i64(eidx);
  const int src = is64 ? eidx[2 * e] : eidx[e];
  const int dst = is64 ? eidx[2 * (E + e)] : eidx[E + e];

  const float hs = h[(long)src * 128 + c];
  const float hd = h[(long)dst * 128 + c];

  const int head = c >> 5, d = c & 31;
  float term = a[head * 64 + d] * hs + a[head * 64 + 32 + d] * hd;
  // reduce over the 32 lanes of this head (heads occupy 32-lane halves)
  term += __shfl_xor(term, 16);
  term += __shfl_xor(term, 8);
  term += __shfl_xor(term, 4);
  term += __shfl_xor(term, 2);
  term += __shfl_xor(term, 1);
  const float attn = term >= 0.f ? term : 0.2f * term;   // leaky_relu(0.2)

  contrib[(long)e * 128 + c] = 0.1f * attn * hs;
}

// Phase B: atomic scatter-add of contributions (duplicate dst handled by HW).
__global__ __launch_bounds__(128) void gat_edge_scatter(
    const int* __restrict__ eidx,
    const float* __restrict__ contrib,
    float* __restrict__ out,
    int E) {
  const int e = blockIdx.x;
  const int c = threadIdx.x;
  const bool is64 = detect_i64(eidx);
  const int dst = is64 ? eidx[2 * (E + e)] : eidx[E + e];
  atomicAdd(&out[(long)dst * 128 + c], contrib[(long)e * 128 + c]);
}

extern "C" void kernel_launch(void* const* d_in, const int* in_sizes, int n_in,
                              void* d_out, int out_size, void* d_ws, size_t ws_size,
                              hipStream_t stream) {
  const float* x  = (const float*)d_in[0];
  const int* eidx = (const int*)d_in[1];
  const float* W  = (const float*)d_in[2];
  const float* a  = (const float*)d_in[3];
  float* out = (float*)d_out;
  float* contrib = (float*)d_ws;     // needs E*128*4 = 256 KB

  const int N = in_sizes[0] / 128;   // 200000
  const int E = in_sizes[1] / 2;     // 500

  // 1024 blocks = 4 blocks/CU (LDS 40960 = 160K/4, VGPR <= 128) -> 16 w/CU.
  int blocks = 1024;                 // % 8 == 0 for the XCD swizzle
  gat_gemm_kernel<<<blocks, 256, 0, stream>>>(x, W, out, N);
  gat_edge_attn<<<E, 128, 0, stream>>>(eidx, a, out, contrib, E);
  gat_edge_scatter<<<E, 128, 0, stream>>>(eidx, contrib, out, E);
}

// Round 13
// 192.378 us; speedup vs baseline: 1.0273x; 1.0273x over previous
//
#include <hip/hip_runtime.h>
#include <hip/hip_bf16.h>

// GAT layer: out = h = x @ W^T  (N=200000 x 128, fp32 in / fp32 out), then
// E=500 edges: out[dst] += 0.1 * leaky_relu(attn, 0.2) * h[src].
//
// K1 evidence matrix (13 rounds): ALL clean-traffic configs pinned at
// 2.05-2.46 TB/s across load shape, store shape, prefetch depth, barriers,
// line-MLP, occupancy up to 16 waves/CU. References on same chip/context:
// fill 6.4 TB/s, m13 copy 6.29 TB/s -- tiny-footprint kernels at ~32 w/CU.
// R12 (this design) NaN'd: raw s_barrier at B2/B4 without lgkmcnt(0) +
// "memory" clobber -- a wave can cross s_barrier with ds_reads issued but
// unserviced (and LLVM may reorder DS ops across a bare s_barrier, rule
// #18 class); another wave's post-barrier LDS write then races the pending
// read -> garbage/NaN. R10 survived the same pattern on scheduling luck.
// R13 = R12 with ALL four barriers hardened (lgkmcnt(0) + sched_barrier
// before s_barrier; vmcnt still never drained in-loop). Tests the last
// occupancy cell: 32 waves/CU.
//   - 512 thr x 1024 blk; 16-row tile/block-iter; one float4/thread/phase
//   - Ws 32768 B XOR-swizzled + XsB 8192 B (bf16 stage / f32 scratch)
//     = 40960 B = 160K/4 -> 4 blocks/CU x 8 waves = 32 waves/CU (HW max)
//   - wave w owns out-cols [16w,16w+16): acc[1], 4 MFMA/tile/wave
// K2/K3 unchanged (race-free two-phase edge update).

typedef __attribute__((ext_vector_type(8))) short bf16x8;   // 8 bf16 = 4 VGPRs
typedef __attribute__((ext_vector_type(4))) float f32x4;

// Hardened barrier: this wave's DS ops serviced + compiler may not move
// memory ops across, THEN rendezvous. vmcnt untouched (prefetch lives).
#define LDS_BARRIER()                                          \
  do {                                                         \
    asm volatile("s_waitcnt lgkmcnt(0)" ::: "memory");         \
    __builtin_amdgcn_sched_barrier(0);                         \
    __builtin_amdgcn_s_barrier();                              \
    __builtin_amdgcn_sched_barrier(0);                         \
  } while (0)

__global__ __launch_bounds__(512, 8) void gat_gemm_kernel(
    const float* __restrict__ x,
    const float* __restrict__ W,
    float* __restrict__ out,
    int N) {
  __shared__ __align__(16) char WsB[32768];   // W bf16, XOR-swizzled rows
  __shared__ __align__(16) char XsB[8192];    // bf16 x-stage / f32 store scratch

  const int tid = threadIdx.x;                // 0..511

  // ---- Stage W (128x128 fp32) -> WsB bf16, XOR-swizzled. One-time. ----
  #pragma unroll
  for (int it = 0; it < 8; ++it) {
    int seg = it * 512 + tid;          // 0..4095 4-float segments
    int row = seg >> 5;                // 32 segs per 128-col row
    int o8 = seg & 31;                 // 8-byte slot within row
    float4 v = *reinterpret_cast<const float4*>(&W[row * 128 + o8 * 4]);
    union { ushort4 u4; __hip_bfloat16 h[4]; } wpk;
    wpk.h[0] = __float2bfloat16(v.x);
    wpk.h[1] = __float2bfloat16(v.y);
    wpk.h[2] = __float2bfloat16(v.z);
    wpk.h[3] = __float2bfloat16(v.w);
    *reinterpret_cast<ushort4*>(
        WsB + row * 256 + ((o8 * 8) ^ ((row & 7) << 4))) = wpk.u4;
  }
  __syncthreads();   // one-time full sync

  const int wave = tid >> 6;   // 0..7: owns out-cols [16*wave, 16*wave+16)
  const int lane = tid & 63;
  const int m = lane & 15;     // out row within tile / W-frag row index
  const int q = lane >> 4;     // quad: k-subchunk q*8, D reg row q*4+j

  const int T16 = N >> 4;                // 16-row tiles: 12500
  const int stride = (int)gridDim.x;     // 1024
  int t = (int)blockIdx.x;               // block-uniform loop

  // ---- prologue: contiguous tile load, ONE float4 per thread (8 KB). ----
  float4 raw;
  raw = *reinterpret_cast<const float4*>(x + (long)t * 2048 + tid * 4);

  while (true) {
    // ---- pack raw -> XsB (bf16, XOR-swizzled 256 B rows). ----
    {
      int row = tid >> 5, o8 = tid & 31;
      union { ushort4 u4; __hip_bfloat16 h[4]; } p;
      p.h[0] = __float2bfloat16(raw.x);
      p.h[1] = __float2bfloat16(raw.y);
      p.h[2] = __float2bfloat16(raw.z);
      p.h[3] = __float2bfloat16(raw.w);
      *reinterpret_cast<ushort4*>(
          XsB + row * 256 + ((o8 * 8) ^ ((row & 7) << 4))) = p.u4;
    }

    // ---- issue next tile's load (in flight across compute+store). ----
    const int tn = t + stride;
    if (tn < T16)
      raw = *reinterpret_cast<const float4*>(x + (long)tn * 2048 + tid * 4);

    // B1: x-stage visible to all waves.
    LDS_BARRIER();

    // ---- fragments + MFMA: wave w computes out cols 16w..16w+15. ----
    bf16x8 af[4];
    #pragma unroll
    for (int s = 0; s < 4; ++s)
      af[s] = *reinterpret_cast<const bf16x8*>(
          XsB + m * 256 + ((s * 64 + q * 16) ^ ((m & 7) << 4)));

    f32x4 acc = (f32x4){0.f, 0.f, 0.f, 0.f};
    #pragma unroll
    for (int s = 0; s < 4; ++s) {
      bf16x8 wfrag = *reinterpret_cast<const bf16x8*>(
          WsB + (wave * 16 + m) * 256 + ((s * 64 + q * 16) ^ ((m & 7) << 4)));
      acc = __builtin_amdgcn_mfma_f32_16x16x32_bf16(wfrag, af[s], acc, 0, 0, 0);
    }

    // B2: every wave's x-stage reads SERVICED (lgkmcnt(0)) before any wave
    // may overwrite XsB as scratch. (R12's raw s_barrier here -> NaN race.)
    LDS_BARRIER();

    // ---- scratch write: D(reg j, lane) -> row m, col wave*16+q*4+j. ----
    *reinterpret_cast<f32x4*>(
        XsB + m * 512 + ((wave * 64 + q * 16) ^ ((m & 7) << 4))) = acc;

    // B3: scratch visible to all waves.
    LDS_BARRIER();

    // ---- coalesced store: ONE f32x4 per thread (8 KB contiguous). ----
    {
      int r = tid >> 5, c = tid & 31;
      f32x4 v = *reinterpret_cast<const f32x4*>(
          XsB + r * 512 + ((c * 16) ^ ((r & 7) << 4)));
      *reinterpret_cast<f32x4*>((char*)out + (long)t * 8192 + tid * 16) = v;
    }

    // B4: every wave's scratch reads serviced before next pack reuses XsB.
    LDS_BARRIER();

    if (tn >= T16) break;
    t = tn;
  }
}

__device__ __forceinline__ int detect_i64(const int* eidx) {
  int or_odd = 0;
  #pragma unroll
  for (int k = 0; k < 16; ++k) or_odd |= eidx[2 * k + 1];
  return or_odd == 0;   // int64 little-endian: high words all zero
}

// Phase A: one block per edge. Read h rows from `out` (pure read), compute
// attn, write contribution vector 0.1*attn*h_src to ws. No races.
__global__ __launch_bounds__(128) void gat_edge_attn(
    const int* __restrict__ eidx,
    const float* __restrict__ a,       // [4, 64]
    const float* __restrict__ h,       // == out, post-GEMM
    float* __restrict__ contrib,       // [E, 128] in ws
    int E) {
  const int e = blockIdx.x;
  const int c = threadIdx.x;
  const bool is64 = detect_i64(eidx);
  const int src = is64 ? eidx[2 * e] : eidx[e];
  const int dst = is64 ? eidx[2 * (E + e)] : eidx[E + e];

  const float hs = h[(long)src * 128 + c];
  const float hd = h[(long)dst * 128 + c];

  const int head = c >> 5, d = c & 31;
  float term = a[head * 64 + d] * hs + a[head * 64 + 32 + d] * hd;
  // reduce over the 32 lanes of this head (heads occupy 32-lane halves)
  term += __shfl_xor(term, 16);
  term += __shfl_xor(term, 8);
  term += __shfl_xor(term, 4);
  term += __shfl_xor(term, 2);
  term += __shfl_xor(term, 1);
  const float attn = term >= 0.f ? term : 0.2f * term;   // leaky_relu(0.2)

  contrib[(long)e * 128 + c] = 0.1f * attn * hs;
}

// Phase B: atomic scatter-add of contributions (duplicate dst handled by HW).
__global__ __launch_bounds__(128) void gat_edge_scatter(
    const int* __restrict__ eidx,
    const float* __restrict__ contrib,
    float* __restrict__ out,
    int E) {
  const int e = blockIdx.x;
  const int c = threadIdx.x;
  const bool is64 = detect_i64(eidx);
  const int dst = is64 ? eidx[2 * (E + e)] : eidx[E + e];
  atomicAdd(&out[(long)dst * 128 + c], contrib[(long)e * 128 + c]);
}

extern "C" void kernel_launch(void* const* d_in, const int* in_sizes, int n_in,
                              void* d_out, int out_size, void* d_ws, size_t ws_size,
                              hipStream_t stream) {
  const float* x  = (const float*)d_in[0];
  const int* eidx = (const int*)d_in[1];
  const float* W  = (const float*)d_in[2];
  const float* a  = (const float*)d_in[3];
  float* out = (float*)d_out;
  float* contrib = (float*)d_ws;     // needs E*128*4 = 256 KB

  const int N = in_sizes[0] / 128;   // 200000
  const int E = in_sizes[1] / 2;     // 500

  // 1024 blocks x 512 threads: 4 blocks/CU (LDS 40960, VGPR<=64)
  // = 32 waves/CU, the hardware maximum.
  int blocks = 1024;
  gat_gemm_kernel<<<blocks, 512, 0, stream>>>(x, W, out, N);
  gat_edge_attn<<<E, 128, 0, stream>>>(eidx, a, out, contrib, E);
  gat_edge_scatter<<<E, 128, 0, stream>>>(eidx, contrib, out, E);
}